// Round 5
// baseline (1097.385 us; speedup 1.0000x reference)
//
#include <hip/hip_runtime.h>
#include <hip/hip_bf16.h>
#include <string.h>

// Batched GEMM: out[b,o,f] = sum_i W[b,o,i] * x[b,i,f]
// B=32, M(O)=1024, K(I)=1024, N(F)=2048, fp32 in/out, bf16 MFMA compute.
//
// Round-5: 256x256 tile, 512 threads (8 waves, wave tile 128x64), BK=32,
// both operands reg-staged (coalesced) -> cvt_pk_bf16 -> LDS.
// LDS rows stride 36 ushorts (18 banks, gcd(18,32)=2): 16 consecutive rows
// hit 16 distinct even bank-starts -> all access classes <=2-way (free),
// NO XOR swizzle needed. LDS 72KB -> 2 blocks/CU resident (cross-block
// overlap hides barrier drains). XCD-chunked block swizzle (T1) for L2
// W-panel reuse. Double-buffered, one barrier per K-step, t+2 loads in
// flight under tile-t MFMA.

typedef float  f32x2 __attribute__((ext_vector_type(2)));
typedef float  f32x4 __attribute__((ext_vector_type(4)));
typedef short  bf16x8 __attribute__((ext_vector_type(8)));
typedef unsigned int u32;

#define BATCH 32
#define MDIM 1024
#define KDIM 1024
#define NDIM 2048
#define BM 256
#define BN 256
#define BK 32
#define NT (KDIM / BK)   // 32 K-steps
#define LSTR 36          // ushorts per LDS row: 32 data + 4 pad (18 banks)

__device__ __forceinline__ u32 cvt2(float a, float b) {
    float2 t; t.x = a; t.y = b;
    __hip_bfloat162 h = __float22bfloat162_rn(t);   // v_cvt_pk_bf16_f32 (RTNE)
    u32 r; memcpy(&r, &h, 4);
    return r;
}

__global__ __launch_bounds__(512, 4) void bgemm_bf16_kernel(
    const float* __restrict__ x, const float* __restrict__ w,
    float* __restrict__ out)
{
    __shared__ unsigned short Ab[2][BM * LSTR];   // W tile  [m][k]  36 KB
    __shared__ unsigned short Bb[2][BN * LSTR];   // x tile^T [n][k] 36 KB

    // ---- XCD-chunked bijective block swizzle (1024 blocks, 1024%8==0) ----
    const int bid  = blockIdx.x;
    const int lbid = (bid & 7) * 128 + (bid >> 3);
    const int bx = lbid & 7;          // n-tile
    const int by = (lbid >> 3) & 3;   // m-tile
    const int bz = lbid >> 5;         // batch

    const int tid = threadIdx.x;
    const int m0  = by * BM;
    const int n0  = bx * BN;

    const int lane = tid & 63;
    const int wid  = tid >> 6;
    const int wm   = (wid >> 2) * 128;   // wave tile 128x64
    const int wn   = (wid & 3)  * 64;
    const int l15  = lane & 15;
    const int kg8  = (lane >> 4) * 8;

    const float* Ag = w + (size_t)bz * MDIM * KDIM + (size_t)m0 * KDIM;
    const float* Bg = x + (size_t)bz * KDIM * NDIM + n0;
    float*       Cg = out + (size_t)bz * MDIM * NDIM + (size_t)m0 * NDIM + n0;

    // ---- A staging map: thread -> rows (tid>>3)+64i, f32x4 col tid&7 ----
    const int a_k4 = tid & 7;
    const int a_m0 = tid >> 3;           // 0..63
    int a_idx[4];
    #pragma unroll
    for (int i = 0; i < 4; ++i)
        a_idx[i] = (a_m0 + 64 * i) * LSTR + 4 * a_k4;
    // ---- B staging map: thread -> k rows 8*(tid>>7)+j, n cols 2*(tid&127) ----
    const int bn0  = 2 * (tid & 127);
    const int b_k0 = 8 * (tid >> 7);     // 0,8,16,24
    int b_idx[2];
    #pragma unroll
    for (int c = 0; c < 2; ++c)
        b_idx[c] = (bn0 + c) * LSTR + b_k0;
    // ---- frag read addrs ----
    int rd_a[8], rd_b[4];
    #pragma unroll
    for (int mi = 0; mi < 8; ++mi)
        rd_a[mi] = (wm + mi * 16 + l15) * LSTR + kg8;
    #pragma unroll
    for (int ni = 0; ni < 4; ++ni)
        rd_b[ni] = (wn + ni * 16 + l15) * LSTR + kg8;

    const float* Ap = Ag + (size_t)a_m0 * KDIM + 4 * a_k4;
    const float* Bp = Bg + (size_t)b_k0 * NDIM + bn0;

    f32x4 acc[8][4];
    #pragma unroll
    for (int i = 0; i < 8; ++i)
        #pragma unroll
        for (int j = 0; j < 4; ++j)
            acc[i][j] = f32x4{0.f, 0.f, 0.f, 0.f};

    f32x4 aav[4];
    f32x2 bbv[8];

    auto load_regs = [&](int kt) {
        #pragma unroll
        for (int i = 0; i < 4; ++i)
            aav[i] = *reinterpret_cast<const f32x4*>(Ap + (size_t)(64 * i) * KDIM + kt);
        #pragma unroll
        for (int j = 0; j < 8; ++j)
            bbv[j] = *reinterpret_cast<const f32x2*>(Bp + (size_t)(kt + j) * NDIM);
    };
    auto stage = [&](int s) {
        #pragma unroll
        for (int i = 0; i < 4; ++i) {
            uint2 v = make_uint2(cvt2(aav[i][0], aav[i][1]),
                                 cvt2(aav[i][2], aav[i][3]));
            *reinterpret_cast<uint2*>(&Ab[s][a_idx[i]]) = v;   // ds_write_b64
        }
        #pragma unroll
        for (int c = 0; c < 2; ++c) {
            uint4 v = make_uint4(cvt2(bbv[0][c], bbv[1][c]),
                                 cvt2(bbv[2][c], bbv[3][c]),
                                 cvt2(bbv[4][c], bbv[5][c]),
                                 cvt2(bbv[6][c], bbv[7][c]));
            *reinterpret_cast<uint4*>(&Bb[s][b_idx[c]]) = v;   // ds_write_b128
        }
    };
    auto compute = [&](int s) {
        bf16x8 bfr[4];
        #pragma unroll
        for (int ni = 0; ni < 4; ++ni)
            bfr[ni] = *reinterpret_cast<const bf16x8*>(&Bb[s][rd_b[ni]]);
        #pragma unroll
        for (int mi = 0; mi < 8; ++mi) {
            bf16x8 af = *reinterpret_cast<const bf16x8*>(&Ab[s][rd_a[mi]]);
            #pragma unroll
            for (int ni = 0; ni < 4; ++ni)
                acc[mi][ni] = __builtin_amdgcn_mfma_f32_16x16x32_bf16(
                    af, bfr[ni], acc[mi][ni], 0, 0, 0);
        }
    };

    // ---- prologue ----
    load_regs(0);
    stage(0);
    load_regs(BK);
    __syncthreads();

    // ---- main loop ----
    for (int t = 0; t < NT - 1; ++t) {
        const int cur = t & 1;
        stage(cur ^ 1);                       // tile t+1 -> other buffer
        int kt2 = (t + 2) * BK;               // issue loads for t+2
        if (kt2 > KDIM - BK) kt2 = KDIM - BK; // clamp (last value unused)
        load_regs(kt2);
        compute(cur);                         // tile t
        __syncthreads();
    }
    compute((NT - 1) & 1);                    // last tile

    // ---- C store: D layout col=lane&15, row=(lane>>4)*4+reg ----
    const int rbase = (lane >> 4) * 4;
    #pragma unroll
    for (int mi = 0; mi < 8; ++mi) {
        #pragma unroll
        for (int ni = 0; ni < 4; ++ni) {
            int n  = wn + ni * 16 + l15;
            int mb = wm + mi * 16 + rbase;
            #pragma unroll
            for (int r = 0; r < 4; ++r)
                Cg[(size_t)(mb + r) * NDIM + n] = acc[mi][ni][r];
        }
    }
}

extern "C" void kernel_launch(void* const* d_in, const int* in_sizes, int n_in,
                              void* d_out, int out_size, void* d_ws, size_t ws_size,
                              hipStream_t stream) {
    const float* x = (const float*)d_in[0];   // [32][1024][2048]
    const float* w = (const float*)d_in[1];   // [32][1024][1024]
    float* out = (float*)d_out;               // [32][1024][2048]
    const int nblocks = (NDIM / BN) * (MDIM / BM) * BATCH;  // 8*4*32 = 1024
    bgemm_bf16_kernel<<<dim3(nblocks), dim3(512), 0, stream>>>(x, w, out);
}

// Round 6
// 243.527 us; speedup vs baseline: 4.5062x; 4.5062x over previous
//
#include <hip/hip_runtime.h>
#include <hip/hip_bf16.h>
#include <string.h>

// Batched GEMM: out[b,o,f] = sum_i W[b,o,i] * x[b,i,f]
// B=32, M(O)=1024, K(I)=1024, N(F)=2048, fp32 in/out, bf16 MFMA compute.
//
// Round-6: round-4 structure (256x256 tile, 512 thr, 8 waves, BK=32,
// reg-staged cvt_pk -> LDS, double-buffered, t+2 prefetch) with:
//  - launch_bounds(512,2)  [round-5's (512,4) forced spills: 2.7GB scratch]
//  - LSTR=36 (18-bank rows, <=2-way on reads/B-writes, <=3-way on A-writes)
//  - XCD-chunked block swizzle
//  - NEW: raw s_barrier + manual lgkmcnt(0) only -> global prefetch loads
//    stay in flight across the barrier (no vmcnt(0) drain per K-step).

typedef float  f32x2 __attribute__((ext_vector_type(2)));
typedef float  f32x4 __attribute__((ext_vector_type(4)));
typedef short  bf16x8 __attribute__((ext_vector_type(8)));
typedef unsigned int u32;

#define BATCH 32
#define MDIM 1024
#define KDIM 1024
#define NDIM 2048
#define BM 256
#define BN 256
#define BK 32
#define NT (KDIM / BK)   // 32 K-steps
#define LSTR 36          // ushorts per LDS row: 32 data + 4 pad (18 banks)

__device__ __forceinline__ u32 cvt2(float a, float b) {
    float2 t; t.x = a; t.y = b;
    __hip_bfloat162 h = __float22bfloat162_rn(t);   // v_cvt_pk_bf16_f32 (RTNE)
    u32 r; memcpy(&r, &h, 4);
    return r;
}

// Barrier that does NOT drain vmcnt: LDS visibility only.
__device__ __forceinline__ void lds_barrier() {
    asm volatile("s_waitcnt lgkmcnt(0)" ::: "memory");
    __builtin_amdgcn_s_barrier();
    asm volatile("" ::: "memory");
}

__global__ __launch_bounds__(512, 2) void bgemm_bf16_kernel(
    const float* __restrict__ x, const float* __restrict__ w,
    float* __restrict__ out)
{
    __shared__ unsigned short Ab[2][BM * LSTR];   // W tile  [m][k]  36 KB
    __shared__ unsigned short Bb[2][BN * LSTR];   // x tile^T [n][k] 36 KB

    // ---- XCD-chunked bijective block swizzle (1024 blocks, 1024%8==0) ----
    const int bid  = blockIdx.x;
    const int lbid = (bid & 7) * 128 + (bid >> 3);
    const int bx = lbid & 7;          // n-tile
    const int by = (lbid >> 3) & 3;   // m-tile
    const int bz = lbid >> 5;         // batch

    const int tid = threadIdx.x;
    const int m0  = by * BM;
    const int n0  = bx * BN;

    const int lane = tid & 63;
    const int wid  = tid >> 6;
    const int wm   = (wid >> 2) * 128;   // wave tile 128x64
    const int wn   = (wid & 3)  * 64;
    const int l15  = lane & 15;
    const int kg8  = (lane >> 4) * 8;

    const float* Ag = w + (size_t)bz * MDIM * KDIM + (size_t)m0 * KDIM;
    const float* Bg = x + (size_t)bz * KDIM * NDIM + n0;
    float*       Cg = out + (size_t)bz * MDIM * NDIM + (size_t)m0 * NDIM + n0;

    // ---- A staging map: thread -> rows (tid>>3)+64i, f32x4 col tid&7 ----
    const int a_k4 = tid & 7;
    const int a_m0 = tid >> 3;           // 0..63
    int a_idx[4];
    #pragma unroll
    for (int i = 0; i < 4; ++i)
        a_idx[i] = (a_m0 + 64 * i) * LSTR + 4 * a_k4;
    // ---- B staging map: thread -> k rows 8*(tid>>7)+j, n cols 2*(tid&127) ----
    const int bn0  = 2 * (tid & 127);
    const int b_k0 = 8 * (tid >> 7);     // 0,8,16,24
    int b_idx[2];
    #pragma unroll
    for (int c = 0; c < 2; ++c)
        b_idx[c] = (bn0 + c) * LSTR + b_k0;
    // ---- frag read addrs ----
    int rd_a[8], rd_b[4];
    #pragma unroll
    for (int mi = 0; mi < 8; ++mi)
        rd_a[mi] = (wm + mi * 16 + l15) * LSTR + kg8;
    #pragma unroll
    for (int ni = 0; ni < 4; ++ni)
        rd_b[ni] = (wn + ni * 16 + l15) * LSTR + kg8;

    const float* Ap = Ag + (size_t)a_m0 * KDIM + 4 * a_k4;
    const float* Bp = Bg + (size_t)b_k0 * NDIM + bn0;

    f32x4 acc[8][4];
    #pragma unroll
    for (int i = 0; i < 8; ++i)
        #pragma unroll
        for (int j = 0; j < 4; ++j)
            acc[i][j] = f32x4{0.f, 0.f, 0.f, 0.f};

    f32x4 aav[4];
    f32x2 bbv[8];

    auto load_regs = [&](int kt) {
        #pragma unroll
        for (int i = 0; i < 4; ++i)
            aav[i] = *reinterpret_cast<const f32x4*>(Ap + (size_t)(64 * i) * KDIM + kt);
        #pragma unroll
        for (int j = 0; j < 8; ++j)
            bbv[j] = *reinterpret_cast<const f32x2*>(Bp + (size_t)(kt + j) * NDIM);
    };
    auto stage = [&](int s) {
        #pragma unroll
        for (int i = 0; i < 4; ++i) {
            uint2 v = make_uint2(cvt2(aav[i][0], aav[i][1]),
                                 cvt2(aav[i][2], aav[i][3]));
            *reinterpret_cast<uint2*>(&Ab[s][a_idx[i]]) = v;   // ds_write_b64
        }
        #pragma unroll
        for (int c = 0; c < 2; ++c) {
            uint4 v = make_uint4(cvt2(bbv[0][c], bbv[1][c]),
                                 cvt2(bbv[2][c], bbv[3][c]),
                                 cvt2(bbv[4][c], bbv[5][c]),
                                 cvt2(bbv[6][c], bbv[7][c]));
            *reinterpret_cast<uint4*>(&Bb[s][b_idx[c]]) = v;   // ds_write_b128
        }
    };
    auto compute = [&](int s) {
        bf16x8 bfr[4];
        #pragma unroll
        for (int ni = 0; ni < 4; ++ni)
            bfr[ni] = *reinterpret_cast<const bf16x8*>(&Bb[s][rd_b[ni]]);
        #pragma unroll
        for (int mi = 0; mi < 8; ++mi) {
            bf16x8 af = *reinterpret_cast<const bf16x8*>(&Ab[s][rd_a[mi]]);
            #pragma unroll
            for (int ni = 0; ni < 4; ++ni)
                acc[mi][ni] = __builtin_amdgcn_mfma_f32_16x16x32_bf16(
                    af, bfr[ni], acc[mi][ni], 0, 0, 0);
        }
    };

    // ---- prologue ----
    load_regs(0);
    stage(0);
    load_regs(BK);
    lds_barrier();

    // ---- main loop ----
    for (int t = 0; t < NT - 1; ++t) {
        const int cur = t & 1;
        stage(cur ^ 1);                       // tile t+1 -> other buffer
        int kt2 = (t + 2) * BK;               // issue loads for t+2
        if (kt2 > KDIM - BK) kt2 = KDIM - BK; // clamp (last value unused)
        load_regs(kt2);
        compute(cur);                         // tile t
        lds_barrier();
    }
    compute((NT - 1) & 1);                    // last tile

    // ---- C store: D layout col=lane&15, row=(lane>>4)*4+reg ----
    const int rbase = (lane >> 4) * 4;
    #pragma unroll
    for (int mi = 0; mi < 8; ++mi) {
        #pragma unroll
        for (int ni = 0; ni < 4; ++ni) {
            int n  = wn + ni * 16 + l15;
            int mb = wm + mi * 16 + rbase;
            #pragma unroll
            for (int r = 0; r < 4; ++r)
                Cg[(size_t)(mb + r) * NDIM + n] = acc[mi][ni][r];
        }
    }
}

extern "C" void kernel_launch(void* const* d_in, const int* in_sizes, int n_in,
                              void* d_out, int out_size, void* d_ws, size_t ws_size,
                              hipStream_t stream) {
    const float* x = (const float*)d_in[0];   // [32][1024][2048]
    const float* w = (const float*)d_in[1];   // [32][1024][1024]
    float* out = (float*)d_out;               // [32][1024][2048]
    const int nblocks = (NDIM / BN) * (MDIM / BM) * BATCH;  // 8*4*32 = 1024
    bgemm_bf16_kernel<<<dim3(nblocks), dim3(512), 0, stream>>>(x, w, out);
}